// Round 1
// baseline (7156.838 us; speedup 1.0000x reference)
//
#include <hip/hip_runtime.h>
#include <hip/hip_bf16.h>
#include <math.h>

#define BT 8192      // B*T rows
#define C_ 1024
#define N3 3072
#define T_ 2048
#define H_ 16
#define HS 64

// ---------------- Kernel A: qkv = x @ w_qkv  (f64 accumulate) ----------------
template<typename ST>
__global__ __launch_bounds__(256) void qkv_gemm(const float* __restrict__ X,
                                                const float* __restrict__ W,
                                                ST* __restrict__ QKV) {
  __shared__ double As[16][65];   // [kk][m]
  __shared__ double Bs[16][65];   // [kk][n]
  const int bm = blockIdx.y * 64, bn = blockIdx.x * 64;
  const int tx = threadIdx.x & 15, ty = threadIdx.x >> 4;
  double acc[4][4] = {};
  for (int k0 = 0; k0 < C_; k0 += 16) {
    for (int i = threadIdx.x; i < 64 * 16; i += 256) {
      int m = i >> 4, kk = i & 15;
      As[kk][m] = (double)X[(size_t)(bm + m) * C_ + k0 + kk];
    }
    for (int i = threadIdx.x; i < 16 * 64; i += 256) {
      int kk = i >> 6, n = i & 63;
      Bs[kk][n] = (double)W[(size_t)(k0 + kk) * N3 + bn + n];
    }
    __syncthreads();
#pragma unroll
    for (int kk = 0; kk < 16; ++kk) {
      double a[4], b[4];
#pragma unroll
      for (int i = 0; i < 4; i++) a[i] = As[kk][ty * 4 + i];
#pragma unroll
      for (int j = 0; j < 4; j++) b[j] = Bs[kk][tx * 4 + j];
#pragma unroll
      for (int i = 0; i < 4; i++)
#pragma unroll
        for (int j = 0; j < 4; j++) acc[i][j] = fma(a[i], b[j], acc[i][j]);
    }
    __syncthreads();
  }
  for (int i = 0; i < 4; i++)
    for (int j = 0; j < 4; j++)
      QKV[(size_t)(bm + ty * 4 + i) * N3 + bn + tx * 4 + j] = (ST)acc[i][j];
}

// ---------------- Kernel B: causal (QK^T/8) V, no softmax (f64) ----------------
// logits stored [B,T,C] layout, col = h*64 + d
template<typename ST>
__global__ __launch_bounds__(256) void attn_kernel(const ST* __restrict__ QKV,
                                                   ST* __restrict__ LOGITS) {
  const int qt = blockIdx.x;      // 0..31 (T/64)
  const int bh = blockIdx.y;      // 0..63 (B*H)
  const int b = bh >> 4, h = bh & 15;
  __shared__ double Qs[64][65];
  __shared__ double Ks[64][65];
  __shared__ double Vs[64][65];
  __shared__ double Ss[64][65];
  const int tx = threadIdx.x & 15, ty = threadIdx.x >> 4;
  const int q0 = qt * 64;
  const size_t tokbase = (size_t)b * T_;

  for (int i = threadIdx.x; i < 64 * 64; i += 256) {
    int qi = i >> 6, d = i & 63;
    Qs[qi][d] = (double)QKV[(tokbase + q0 + qi) * N3 + h * HS + d];
  }
  double o[4][4] = {};
  for (int kt = 0; kt <= qt; ++kt) {
    const int k0 = kt * 64;
    __syncthreads();   // Q staged (it 0); prior S/V reads done (it>0)
    for (int i = threadIdx.x; i < 64 * 64; i += 256) {
      int ki = i >> 6, d = i & 63;
      size_t rb = (tokbase + k0 + ki) * N3 + h * HS + d;
      Ks[ki][d] = (double)QKV[rb + C_];
      Vs[ki][d] = (double)QKV[rb + 2 * C_];
    }
    __syncthreads();
    double s[4][4] = {};
#pragma unroll 8
    for (int d = 0; d < 64; ++d) {
      double a[4], c[4];
#pragma unroll
      for (int i = 0; i < 4; i++) a[i] = Qs[ty * 4 + i][d];
#pragma unroll
      for (int j = 0; j < 4; j++) c[j] = Ks[tx * 4 + j][d];
#pragma unroll
      for (int i = 0; i < 4; i++)
#pragma unroll
        for (int j = 0; j < 4; j++) s[i][j] = fma(a[i], c[j], s[i][j]);
    }
#pragma unroll
    for (int i = 0; i < 4; i++)
#pragma unroll
      for (int j = 0; j < 4; j++) {
        int qg = q0 + ty * 4 + i, kg = k0 + tx * 4 + j;
        Ss[ty * 4 + i][tx * 4 + j] = (kg <= qg) ? s[i][j] * 0.125 : 0.0;
      }
    __syncthreads();
#pragma unroll 8
    for (int kk = 0; kk < 64; ++kk) {
      double a[4], c[4];
#pragma unroll
      for (int i = 0; i < 4; i++) a[i] = Ss[ty * 4 + i][kk];
#pragma unroll
      for (int j = 0; j < 4; j++) c[j] = Vs[kk][tx * 4 + j];
#pragma unroll
      for (int i = 0; i < 4; i++)
#pragma unroll
        for (int j = 0; j < 4; j++) o[i][j] = fma(a[i], c[j], o[i][j]);
    }
  }
  for (int i = 0; i < 4; i++)
    for (int j = 0; j < 4; j++)
      LOGITS[(tokbase + q0 + ty * 4 + i) * C_ + h * HS + tx * 4 + j] = (ST)o[i][j];
}

// ---------------- Kernel C: LN + softmax + log-transform + mask ----------------
__device__ __forceinline__ double blockReduceSumD(double val, double* sh) {
#pragma unroll
  for (int off = 32; off > 0; off >>= 1) val += __shfl_down(val, off, 64);
  int wid = threadIdx.x >> 6, lane = threadIdx.x & 63;
  if (lane == 0) sh[wid] = val;
  __syncthreads();
  double total = sh[0] + sh[1] + sh[2] + sh[3];
  __syncthreads();
  return total;
}
__device__ __forceinline__ double blockReduceMaxD(double val, double* sh) {
#pragma unroll
  for (int off = 32; off > 0; off >>= 1) val = fmax(val, __shfl_down(val, off, 64));
  int wid = threadIdx.x >> 6, lane = threadIdx.x & 63;
  if (lane == 0) sh[wid] = val;
  __syncthreads();
  double total = fmax(fmax(sh[0], sh[1]), fmax(sh[2], sh[3]));
  __syncthreads();
  return total;
}

template<typename ST>
__global__ __launch_bounds__(256) void finish_kernel(const ST* __restrict__ LOGITS,
                                                     const float* __restrict__ LNW,
                                                     const float* __restrict__ X,
                                                     const float* __restrict__ NOISE,
                                                     float* __restrict__ OUT,
                                                     double log_scale, double denom) {
  __shared__ double sh[4];
  const int row = blockIdx.x;
  const int t = threadIdx.x;
  const ST* lrow = LOGITS + (size_t)row * C_;
  double v[4];
#pragma unroll
  for (int j = 0; j < 4; j++) v[j] = (double)lrow[t + j * 256];
  double psum = v[0] + v[1] + v[2] + v[3];
  double mu = blockReduceSumD(psum, sh) * (1.0 / 1024.0);
  double d2 = 0.0;
#pragma unroll
  for (int j = 0; j < 4; j++) { double d = v[j] - mu; d2 += d * d; }
  double var = blockReduceSumD(d2, sh) * (1.0 / 1024.0);
  double rstd = 1.0 / sqrt(var + 1e-5);
  double z[4];
#pragma unroll
  for (int j = 0; j < 4; j++)
    z[j] = (v[j] - mu) * rstd * (double)LNW[t + j * 256];
  double zmax = fmax(fmax(z[0], z[1]), fmax(z[2], z[3]));
  double m = blockReduceMaxD(zmax, sh);
  double e[4];
  double esum = 0.0;
#pragma unroll
  for (int j = 0; j < 4; j++) { e[j] = exp(z[j] - m); esum += e[j]; }
  double stot = blockReduceSumD(esum, sh);
#pragma unroll
  for (int j = 0; j < 4; j++) {
    int col = t + j * 256;
    double p = e[j] / stot;
    double sc = log(log_scale * p + 1.0) / denom;
    double comp = 1.0 - sc;
    double nz = (double)NOISE[(size_t)row * C_ + col];
    double maskv = (nz >= comp) ? (comp + sc) : ((comp - 1.0) + sc);
    OUT[(size_t)row * C_ + col] = (float)((double)X[(size_t)row * C_ + col] * maskv);
  }
}

// ---------------- launch ----------------
template<typename ST>
static void run_all(const float* X, const float* W, const float* LNW,
                    const float* NOISE, float* OUT, void* ws, hipStream_t stream) {
  ST* qkv = (ST*)ws;
  ST* logits = (ST*)((char*)ws + sizeof(ST) * (size_t)BT * N3);
  const double e = 1.0 / 1024.0;
  const double ls = (1.0 + sqrt(1.0 - 4.0 * e) - 2.0 * e) / (2.0 * e * e);
  const double denom = log(ls);

  qkv_gemm<ST><<<dim3(N3 / 64, BT / 64), 256, 0, stream>>>(X, W, qkv);
  attn_kernel<ST><<<dim3(T_ / 64, 64), 256, 0, stream>>>(qkv, logits);
  finish_kernel<ST><<<BT, 256, 0, stream>>>(logits, LNW, X, NOISE, OUT, ls, denom);
}

extern "C" void kernel_launch(void* const* d_in, const int* in_sizes, int n_in,
                              void* d_out, int out_size, void* d_ws, size_t ws_size,
                              hipStream_t stream) {
  const float* X = (const float*)d_in[0];
  const float* W = (const float*)d_in[1];
  const float* LNW = (const float*)d_in[2];
  const float* NOISE = (const float*)d_in[3];
  float* OUT = (float*)d_out;

  size_t need64 = 8ull * ((size_t)BT * N3 + (size_t)BT * C_);
  if (ws_size >= need64)
    run_all<double>(X, W, LNW, NOISE, OUT, d_ws, stream);
  else
    run_all<float>(X, W, LNW, NOISE, OUT, d_ws, stream);
}